// Round 2
// baseline (4951.014 us; speedup 1.0000x reference)
//
#include <hip/hip_runtime.h>
#include <math.h>

namespace {
constexpr int kB = 512;
constexpr int kT = 256;
constexpr int kD = 256;
constexpr int kS = 8;
constexpr int kStRow = 292;  // 288 data (physk layout) + 4; 292 % 32 == 4
constexpr int kRedRow = 20;  // reduction table row stride: 16 wave slots + pad

__device__ __forceinline__ int physk(int k) { return k + ((k >> 5) << 2); }

// DPP cross-lane adds (VALU pipe — zero DS traffic, unlike __shfl_xor which
// lowers to ds_swizzle/bpermute on CDNA). Patterns available on gfx9-lineage:
//   0xB1  quad_perm [1,0,3,2]  == xor 1
//   0x4E  quad_perm [2,3,0,1]  == xor 2
//   0x141 row_half_mirror      == xor 7  (within 8 lanes)
//   0x140 row_mirror           == xor 15 (within 16 lanes)
// Tree {1,2,7,15} spans the 16-lane row: after the 4 adds every lane holds
// the full 16-lane sum (1,2 cover the quad; 7 pairs the two quads of the
// 8-group; 15 pairs the two 8-groups).
template <int CTRL>
__device__ __forceinline__ float dpp_add(float v) {
  int p = __builtin_amdgcn_update_dpp(0, __float_as_int(v), CTRL, 0xF, 0xF, false);
  return v + __int_as_float(p);
}
template <int CTRL>
__device__ __forceinline__ float4 dpp_add4(float4 v) {
  float4 r;
  r.x = dpp_add<CTRL>(v.x);
  r.y = dpp_add<CTRL>(v.y);
  r.z = dpp_add<CTRL>(v.z);
  r.w = dpp_add<CTRL>(v.w);
  return r;
}
}

// ---------------------------------------------------------------------------
// Kernel A: XW[b,t,:] = inputs[b,t,:] @ W, skipping t >= lengths[b]. (unchanged)
// ---------------------------------------------------------------------------
__global__ __launch_bounds__(256, 2)
void xw_gemm_kernel(const float* __restrict__ X, const float* __restrict__ W,
                    const int* __restrict__ lengths, float* __restrict__ XW) {
  const int m0 = blockIdx.x * 32;
  const int b = m0 >> 8;
  const int t0 = m0 & 255;
  if (t0 >= lengths[b]) return;

  __shared__ float Xs[32][kD];
  const int tid = threadIdx.x;
  const int j  = tid & 63;
  const int rg = tid >> 6;

  const float4* Xg4 = (const float4*)(X + (size_t)m0 * kD);
  float4* Xs4 = (float4*)&Xs[0][0];
  for (int i = tid; i < 32 * kD / 4; i += 256) Xs4[i] = Xg4[i];
  __syncthreads();

  float4 acc[8];
#pragma unroll
  for (int i = 0; i < 8; ++i) acc[i] = make_float4(0.f, 0.f, 0.f, 0.f);

  const float4* W4 = (const float4*)W;
  const float4* Xrow = (const float4*)&Xs[rg * 8][0];

  for (int k4 = 0; k4 < kD / 4; ++k4) {
    float4 w0 = W4[(size_t)(4 * k4 + 0) * 64 + j];
    float4 w1 = W4[(size_t)(4 * k4 + 1) * 64 + j];
    float4 w2 = W4[(size_t)(4 * k4 + 2) * 64 + j];
    float4 w3 = W4[(size_t)(4 * k4 + 3) * 64 + j];
#pragma unroll
    for (int i = 0; i < 8; ++i) {
      float4 x = Xrow[i * 64 + k4];
      acc[i].x = fmaf(x.x, w0.x, fmaf(x.y, w1.x, fmaf(x.z, w2.x, fmaf(x.w, w3.x, acc[i].x))));
      acc[i].y = fmaf(x.x, w0.y, fmaf(x.y, w1.y, fmaf(x.z, w2.y, fmaf(x.w, w3.y, acc[i].y))));
      acc[i].z = fmaf(x.x, w0.z, fmaf(x.y, w1.z, fmaf(x.z, w2.z, fmaf(x.w, w3.z, acc[i].z))));
      acc[i].w = fmaf(x.x, w0.w, fmaf(x.y, w1.w, fmaf(x.z, w2.w, fmaf(x.w, w3.w, acc[i].w))));
    }
  }
  float4* XW4 = (float4*)XW;
#pragma unroll
  for (int i = 0; i < 8; ++i)
    XW4[(size_t)(m0 + rg * 8 + i) * 64 + j] = acc[i];
}

// ---------------------------------------------------------------------------
// Kernel B: GK[b,t,s] = inputs[b,t,:] . keys[s,:], t < lengths[b] only. (unchanged)
// ---------------------------------------------------------------------------
__global__ __launch_bounds__(256, 4)
void gk_kernel(const float* __restrict__ inputs, const float* __restrict__ keys,
               const int* __restrict__ lengths, float* __restrict__ GK) {
  const int b = blockIdx.x;
  const int tid = threadIdx.x;
  const int lane = tid & 63;
  const int wid = tid >> 6;
  const int len = lengths[b];

  __shared__ float4 Ks4[kS * 64];
  for (int i = tid; i < kS * 64; i += 256) Ks4[i] = ((const float4*)keys)[i];
  __syncthreads();

  const float4* X4 = (const float4*)inputs;
  for (int t = wid; t < len; t += 4) {
    float4 x = X4[((size_t)b * kT + t) * 64 + lane];
    float p[kS];
#pragma unroll
    for (int s = 0; s < kS; ++s) {
      float4 kk = Ks4[s * 64 + lane];
      p[s] = fmaf(x.x, kk.x, fmaf(x.y, kk.y, fmaf(x.z, kk.z, x.w * kk.w)));
    }
#pragma unroll
    for (int off = 32; off >= 1; off >>= 1) {
#pragma unroll
      for (int s = 0; s < kS; ++s) p[s] += __shfl_xor(p[s], off, 64);
    }
    if (lane == 0) {
      float* g = GK + ((size_t)b * kT + t) * kS;
#pragma unroll
      for (int s = 0; s < kS; ++s) g[s] = p[s];
    }
  }
}

// ---------------------------------------------------------------------------
// Kernel S: rank lengths descending (stable). order[r] = batch with rank r.
// ---------------------------------------------------------------------------
__global__ __launch_bounds__(512)
void sort_lengths_kernel(const int* __restrict__ lengths, int* __restrict__ order) {
  __shared__ int L[kB];
  const int i = threadIdx.x;
  L[i] = lengths[i];
  __syncthreads();
  const int li = L[i];
  int r = 0;
  for (int j = 0; j < kB; ++j) {
    const int lj = L[j];
    r += (lj > li || (lj == li && j < i)) ? 1 : 0;
  }
  order[r] = i;
}

// ---------------------------------------------------------------------------
// Kernel C (v5): recurrence. 256 blocks x 1024 threads (1 block/CU, 16 waves
// = 4 waves/SIMD -> the immovable 128-VGPR cap is the NATURAL budget, no
// spill). Two sorted-paired batches per block (bA long, bB short; bB drops
// out early, barriers shared).
//   R1 lesson: 512-thr + u4[32] (128 floats) spilled 1.4 GB/dispatch
//   (WRITE_SIZE). -> 64-float U slice per thread is the hard ceiling, which
//   at 4 output cols forces a 16-k chunk and 1024 threads.
// Thread (w=tid>>6, jj=lane>>4, q=lane&15): col-group cg=w*4+jj (cols
// 4cg..4cg+3), k-chunk [16q,16q+16), U slice u4[16]=64 VGPR. State reads are
// 32 b128/thread/batch (half of rec3). k-split reduction over the 16 q-lanes
// uses DPP VALU adds (xor1,xor2,mirror7,mirror15) — zero DS-pipe traffic
// (rec3 burned ~1536 ds_swizzle/step-pair on this). Epilogue s-split: lane
// finalizes s=q&7 (q and q+8 hold identical copies; only q<8 writes).
// Column reductions (gate/norm): shfl_xor 16,32 (over jj) + [8][20] LDS
// tables over the 16 waves.
// ---------------------------------------------------------------------------
__global__ __launch_bounds__(1024)
void dynmem_rec5_kernel(const float* __restrict__ inputs,   // [B,T,D]
                        const int*   __restrict__ lengths,  // [B]
                        const float* __restrict__ keys,     // [S,D]
                        const float* __restrict__ U,        // [D,D]
                        const float* __restrict__ V,        // [D,D]
                        const float* __restrict__ gate_bias,
                        const float* __restrict__ state_bias,
                        const float* __restrict__ XW,       // [B,T,D]
                        const float* __restrict__ GK,       // [B,T,S]
                        const int*   __restrict__ order,    // [B] desc by length
                        float* __restrict__ out)            // [B,S,D]
{
  const int blk = blockIdx.x;
  const int bA = order[blk];
  const int bB = order[kB - 1 - blk];
  const int tid = threadIdx.x;
  const int w = tid >> 6;          // 0..15
  const int lane = tid & 63;
  const int q = lane & 15;         // k-chunk index (16 k each)
  const int jj = lane >> 4;        // 0..3
  const int cg = w * 4 + jj;       // 0..63
  const int c0 = 4 * cg;
  const int c0p = physk(c0);       // 4 cols contiguous within a 32-group
  const int s8 = q & 7;            // state row this lane finalizes

  __shared__ float StA[kS * kStRow];
  __shared__ float StB[kS * kStRow];
  __shared__ float KVL[kS * kD];
  __shared__ float redGA[kS * kRedRow], redGB[kS * kRedRow];
  __shared__ float redNA[kS * kRedRow], redNB[kS * kRedRow];

  // init both states = keys (padded layout)
  for (int i = tid; i < kS * kD; i += 1024) {
    int s = i >> 8, dd = i & 255;
    float kv = keys[i];
    int pa = s * kStRow + physk(dd);
    StA[pa] = kv;
    StB[pa] = kv;
  }

  // persistent U slice: rows 16q..16q+15, cols c0..c0+3 (64 VGPRs)
  float4 u4[16];
  const int kbase = 16 * q;
#pragma unroll
  for (int kk = 0; kk < 16; ++kk)
    u4[kk] = *(const float4*)(U + (size_t)(kbase + kk) * kD + c0);

  // KV[s][d] = (keys @ V)[s][d] + state_bias[d]; thread (h4,d) does rows h4, h4+4.
  {
    const int h4 = tid >> 8, d = tid & 255;   // h4 in 0..3
    float a0 = 0.f, a1 = 0.f;
    const float* Vc = V + d;
    const float* K0 = keys + (size_t)h4 * kD;
    const float* K1 = keys + (size_t)(h4 + 4) * kD;
    for (int k = 0; k < kD; ++k) {
      float v = Vc[(size_t)k * kD];
      a0 = fmaf(K0[k], v, a0);
      a1 = fmaf(K1[k], v, a1);
    }
    float sb = state_bias[d];
    KVL[h4 * kD + d] = a0 + sb;
    KVL[(h4 + 4) * kD + d] = a1 + sb;
  }

  const float gb = gate_bias[0];
  int lenA = lengths[bA]; lenA = lenA < 0 ? 0 : (lenA > kT ? kT : lenA);
  int lenB = lengths[bB]; lenB = lenB < 0 ? 0 : (lenB > kT ? kT : lenB);
  // sorted desc => lenA >= lenB; loop runs lenA steps.

  __syncthreads();  // states + KVL ready

  float4 srA = *(const float4*)(StA + s8 * kStRow + c0p);
  float4 srB = *(const float4*)(StB + s8 * kStRow + c0p);
  const float* SA = StA + physk(kbase);   // physical base of this k-chunk
  const float* SB = StB + physk(kbase);

  for (int t = 0; t < lenA; ++t) {
    const bool dB = t < lenB;
    const size_t baseA = ((size_t)bA * kT + t) * (size_t)kD;
    const size_t baseB = ((size_t)bB * kT + t) * (size_t)kD;

    // ---- gate partials for s=s8 over own 4 state cols ----
    {
      float4 xA = *(const float4*)(inputs + baseA + c0);
      float pg = fmaf(xA.x, srA.x, fmaf(xA.y, srA.y, fmaf(xA.z, srA.z, xA.w * srA.w)));
      pg += __shfl_xor(pg, 16, 64);
      pg += __shfl_xor(pg, 32, 64);
      if (lane < 8) redGA[lane * kRedRow + w] = pg;
    }
    if (dB) {
      float4 xB = *(const float4*)(inputs + baseB + c0);
      float pg = fmaf(xB.x, srB.x, fmaf(xB.y, srB.y, fmaf(xB.z, srB.z, xB.w * srB.w)));
      pg += __shfl_xor(pg, 16, 64);
      pg += __shfl_xor(pg, 32, 64);
      if (lane < 8) redGB[lane * kRedRow + w] = pg;
    }

    // ---- matmul A: C[s][4 cols] over 16-k chunk q ----
    float4 cA = make_float4(0.f, 0.f, 0.f, 0.f);
    float4 cB = make_float4(0.f, 0.f, 0.f, 0.f);
    {
      float4 C[8];
#pragma unroll
      for (int s = 0; s < 8; ++s) C[s] = make_float4(0.f, 0.f, 0.f, 0.f);
#pragma unroll
      for (int k4 = 0; k4 < 4; ++k4) {
        const float4 u0 = u4[4 * k4 + 0], u1 = u4[4 * k4 + 1];
        const float4 u2 = u4[4 * k4 + 2], u3 = u4[4 * k4 + 3];
#pragma unroll
        for (int s = 0; s < 8; ++s) {
          float4 sv = *(const float4*)(SA + s * kStRow + 4 * k4);
          C[s].x = fmaf(sv.x, u0.x, fmaf(sv.y, u1.x, fmaf(sv.z, u2.x, fmaf(sv.w, u3.x, C[s].x))));
          C[s].y = fmaf(sv.x, u0.y, fmaf(sv.y, u1.y, fmaf(sv.z, u2.y, fmaf(sv.w, u3.y, C[s].y))));
          C[s].z = fmaf(sv.x, u0.z, fmaf(sv.y, u1.z, fmaf(sv.z, u2.z, fmaf(sv.w, u3.z, C[s].z))));
          C[s].w = fmaf(sv.x, u0.w, fmaf(sv.y, u1.w, fmaf(sv.z, u2.w, fmaf(sv.w, u3.w, C[s].w))));
        }
      }
      // k-split reduction across 16 q-lanes: pure-VALU DPP tree
#pragma unroll
      for (int s = 0; s < 8; ++s) {
        C[s] = dpp_add4<0xB1>(C[s]);    // xor 1
        C[s] = dpp_add4<0x4E>(C[s]);    // xor 2
        C[s] = dpp_add4<0x141>(C[s]);   // xor 7 (row_half_mirror)
        C[s] = dpp_add4<0x140>(C[s]);   // xor 15 (row_mirror)
      }
      cA = C[0];
#pragma unroll
      for (int s = 1; s < 8; ++s) {
        if (s8 == s) cA = C[s];
      }
    }

    // ---- matmul B ----
    if (dB) {
      float4 C[8];
#pragma unroll
      for (int s = 0; s < 8; ++s) C[s] = make_float4(0.f, 0.f, 0.f, 0.f);
#pragma unroll
      for (int k4 = 0; k4 < 4; ++k4) {
        const float4 u0 = u4[4 * k4 + 0], u1 = u4[4 * k4 + 1];
        const float4 u2 = u4[4 * k4 + 2], u3 = u4[4 * k4 + 3];
#pragma unroll
        for (int s = 0; s < 8; ++s) {
          float4 sv = *(const float4*)(SB + s * kStRow + 4 * k4);
          C[s].x = fmaf(sv.x, u0.x, fmaf(sv.y, u1.x, fmaf(sv.z, u2.x, fmaf(sv.w, u3.x, C[s].x))));
          C[s].y = fmaf(sv.x, u0.y, fmaf(sv.y, u1.y, fmaf(sv.z, u2.y, fmaf(sv.w, u3.y, C[s].y))));
          C[s].z = fmaf(sv.x, u0.z, fmaf(sv.y, u1.z, fmaf(sv.z, u2.z, fmaf(sv.w, u3.z, C[s].z))));
          C[s].w = fmaf(sv.x, u0.w, fmaf(sv.y, u1.w, fmaf(sv.z, u2.w, fmaf(sv.w, u3.w, C[s].w))));
        }
      }
#pragma unroll
      for (int s = 0; s < 8; ++s) {
        C[s] = dpp_add4<0xB1>(C[s]);
        C[s] = dpp_add4<0x4E>(C[s]);
        C[s] = dpp_add4<0x141>(C[s]);
        C[s] = dpp_add4<0x140>(C[s]);
      }
      cB = C[0];
#pragma unroll
      for (int s = 1; s < 8; ++s) {
        if (s8 == s) cB = C[s];
      }
    }

    // epilogue operand loads (issue before the barrier; latency hidden there)
    const float4 xwA = *(const float4*)(XW + baseA + c0);
    const float gkA = GK[((size_t)bA * kT + t) * kS + s8];
    float4 xwB = make_float4(0.f, 0.f, 0.f, 0.f);
    float gkB = 0.f;
    if (dB) {
      xwB = *(const float4*)(XW + baseB + c0);
      gkB = GK[((size_t)bB * kT + t) * kS + s8];
    }

    __syncthreads();  // B1: redG* complete; all St* matmul reads done

    const float4 kvq = *(const float4*)(KVL + s8 * kD + c0);
    float4 hA = make_float4(0.f, 0.f, 0.f, 0.f);
    float4 hB = make_float4(0.f, 0.f, 0.f, 0.f);
    {
      const float* rg = redGA + s8 * kRedRow;
      float4 ra = *(const float4*)(rg);
      float4 rb = *(const float4*)(rg + 4);
      float4 rc = *(const float4*)(rg + 8);
      float4 rd = *(const float4*)(rg + 12);
      float gs = (((ra.x + ra.y) + (ra.z + ra.w)) + ((rb.x + rb.y) + (rb.z + rb.w))) +
                 (((rc.x + rc.y) + (rc.z + rc.w)) + ((rd.x + rd.y) + (rd.z + rd.w))) +
                 gkA + gb;
      float g = 1.f / (1.f + expf(-gs));
      float t0 = cA.x + kvq.x + xwA.x; t0 = t0 > 0.f ? t0 : expm1f(t0);
      float t1 = cA.y + kvq.y + xwA.y; t1 = t1 > 0.f ? t1 : expm1f(t1);
      float t2 = cA.z + kvq.z + xwA.z; t2 = t2 > 0.f ? t2 : expm1f(t2);
      float t3 = cA.w + kvq.w + xwA.w; t3 = t3 > 0.f ? t3 : expm1f(t3);
      hA.x = fmaf(g, t0, srA.x);
      hA.y = fmaf(g, t1, srA.y);
      hA.z = fmaf(g, t2, srA.z);
      hA.w = fmaf(g, t3, srA.w);
      float pn = fmaf(hA.x, hA.x, fmaf(hA.y, hA.y, fmaf(hA.z, hA.z, hA.w * hA.w)));
      pn += __shfl_xor(pn, 16, 64);
      pn += __shfl_xor(pn, 32, 64);
      if (lane < 8) redNA[lane * kRedRow + w] = pn;
    }
    if (dB) {
      const float* rg = redGB + s8 * kRedRow;
      float4 ra = *(const float4*)(rg);
      float4 rb = *(const float4*)(rg + 4);
      float4 rc = *(const float4*)(rg + 8);
      float4 rd = *(const float4*)(rg + 12);
      float gs = (((ra.x + ra.y) + (ra.z + ra.w)) + ((rb.x + rb.y) + (rb.z + rb.w))) +
                 (((rc.x + rc.y) + (rc.z + rc.w)) + ((rd.x + rd.y) + (rd.z + rd.w))) +
                 gkB + gb;
      float g = 1.f / (1.f + expf(-gs));
      float t0 = cB.x + kvq.x + xwB.x; t0 = t0 > 0.f ? t0 : expm1f(t0);
      float t1 = cB.y + kvq.y + xwB.y; t1 = t1 > 0.f ? t1 : expm1f(t1);
      float t2 = cB.z + kvq.z + xwB.z; t2 = t2 > 0.f ? t2 : expm1f(t2);
      float t3 = cB.w + kvq.w + xwB.w; t3 = t3 > 0.f ? t3 : expm1f(t3);
      hB.x = fmaf(g, t0, srB.x);
      hB.y = fmaf(g, t1, srB.y);
      hB.z = fmaf(g, t2, srB.z);
      hB.w = fmaf(g, t3, srB.w);
      float pn = fmaf(hB.x, hB.x, fmaf(hB.y, hB.y, fmaf(hB.z, hB.z, hB.w * hB.w)));
      pn += __shfl_xor(pn, 16, 64);
      pn += __shfl_xor(pn, 32, 64);
      if (lane < 8) redNB[lane * kRedRow + w] = pn;
    }
    __syncthreads();  // B2: redN* complete

    {
      const float* rn = redNA + s8 * kRedRow;
      float4 na = *(const float4*)(rn);
      float4 nb = *(const float4*)(rn + 4);
      float4 nc = *(const float4*)(rn + 8);
      float4 nd = *(const float4*)(rn + 12);
      float ns = (((na.x + na.y) + (na.z + na.w)) + ((nb.x + nb.y) + (nb.z + nb.w))) +
                 (((nc.x + nc.y) + (nc.z + nc.w)) + ((nd.x + nd.y) + (nd.z + nd.w)));
      float inh = 1.f / fmaxf(sqrtf(ns), 1e-12f);
      srA.x = hA.x * inh; srA.y = hA.y * inh; srA.z = hA.z * inh; srA.w = hA.w * inh;
      if (q < 8) *(float4*)(StA + s8 * kStRow + c0p) = srA;
    }
    if (dB) {
      const float* rn = redNB + s8 * kRedRow;
      float4 na = *(const float4*)(rn);
      float4 nb = *(const float4*)(rn + 4);
      float4 nc = *(const float4*)(rn + 8);
      float4 nd = *(const float4*)(rn + 12);
      float ns = (((na.x + na.y) + (na.z + na.w)) + ((nb.x + nb.y) + (nb.z + nb.w))) +
                 (((nc.x + nc.y) + (nc.z + nc.w)) + ((nd.x + nd.y) + (nd.z + nd.w)));
      float inh = 1.f / fmaxf(sqrtf(ns), 1e-12f);
      srB.x = hB.x * inh; srB.y = hB.y * inh; srB.z = hB.z * inh; srB.w = hB.w * inh;
      if (q < 8) *(float4*)(StB + s8 * kStRow + c0p) = srB;
    }
    __syncthreads();  // B3: new states visible for next step
  }

  // final states -> out
  for (int i = tid; i < kS * kD; i += 1024) {
    int s = i >> 8, dd = i & 255;
    int pa = s * kStRow + physk(dd);
    out[(size_t)bA * kS * kD + i] = StA[pa];
    out[(size_t)bB * kS * kD + i] = StB[pa];
  }
}

extern "C" void kernel_launch(void* const* d_in, const int* in_sizes, int n_in,
                              void* d_out, int out_size, void* d_ws, size_t ws_size,
                              hipStream_t stream) {
  const float* inputs     = (const float*)d_in[0];
  const int*   lengths    = (const int*)  d_in[1];
  const float* keys       = (const float*)d_in[2];
  const float* U          = (const float*)d_in[3];
  const float* V          = (const float*)d_in[4];
  const float* W          = (const float*)d_in[5];
  const float* gate_bias  = (const float*)d_in[6];
  const float* state_bias = (const float*)d_in[7];

  const size_t xw_elems = (size_t)kB * kT * kD;
  const size_t gk_elems = (size_t)kB * kT * kS;
  float* XW = (float*)d_ws;
  float* GK = (float*)d_ws + xw_elems;
  int*   order = (int*)((float*)d_ws + xw_elems + gk_elems);

  sort_lengths_kernel<<<dim3(1), dim3(512), 0, stream>>>(lengths, order);
  xw_gemm_kernel<<<dim3((kB * kT) / 32), dim3(256), 0, stream>>>(inputs, W, lengths, XW);
  gk_kernel<<<dim3(kB), dim3(256), 0, stream>>>(inputs, keys, lengths, GK);
  dynmem_rec5_kernel<<<dim3(kB / 2), dim3(1024), 0, stream>>>(
      inputs, lengths, keys, U, V, gate_bias, state_bias, XW, GK, order, (float*)d_out);
}

// Round 3
// 4751.477 us; speedup vs baseline: 1.0420x; 1.0420x over previous
//
#include <hip/hip_runtime.h>
#include <math.h>

namespace {
constexpr int kB = 512;
constexpr int kT = 256;
constexpr int kD = 256;
constexpr int kS = 8;
constexpr int kStRow = 292;  // 288 data (physk layout) + 4; 292 % 32 == 4
constexpr int kRedRow = 20;  // reduction table row stride: 16 wave slots + pad

__device__ __forceinline__ int physk(int k) { return k + ((k >> 5) << 2); }

// DPP cross-lane adds (VALU pipe — zero DS traffic). Verified on HW in R2.
//   0xB1  quad_perm [1,0,3,2]  == xor 1
//   0x4E  quad_perm [2,3,0,1]  == xor 2
//   0x141 row_half_mirror      == xor 7 (valid once quads are uniform)
//   0x140 row_mirror           == xor 15 (valid once 8-groups are uniform)
template <int CTRL>
__device__ __forceinline__ float dpp_add(float v) {
  int p = __builtin_amdgcn_update_dpp(0, __float_as_int(v), CTRL, 0xF, 0xF, false);
  return v + __int_as_float(p);
}
template <int CTRL>
__device__ __forceinline__ float4 dpp_add4(float4 v) {
  float4 r;
  r.x = dpp_add<CTRL>(v.x);
  r.y = dpp_add<CTRL>(v.y);
  r.z = dpp_add<CTRL>(v.z);
  r.w = dpp_add<CTRL>(v.w);
  return r;
}
}

// ---------------------------------------------------------------------------
// Kernel A: XW[b,t,:] = inputs[b,t,:] @ W, skipping t >= lengths[b]. (unchanged)
// ---------------------------------------------------------------------------
__global__ __launch_bounds__(256, 2)
void xw_gemm_kernel(const float* __restrict__ X, const float* __restrict__ W,
                    const int* __restrict__ lengths, float* __restrict__ XW) {
  const int m0 = blockIdx.x * 32;
  const int b = m0 >> 8;
  const int t0 = m0 & 255;
  if (t0 >= lengths[b]) return;

  __shared__ float Xs[32][kD];
  const int tid = threadIdx.x;
  const int j  = tid & 63;
  const int rg = tid >> 6;

  const float4* Xg4 = (const float4*)(X + (size_t)m0 * kD);
  float4* Xs4 = (float4*)&Xs[0][0];
  for (int i = tid; i < 32 * kD / 4; i += 256) Xs4[i] = Xg4[i];
  __syncthreads();

  float4 acc[8];
#pragma unroll
  for (int i = 0; i < 8; ++i) acc[i] = make_float4(0.f, 0.f, 0.f, 0.f);

  const float4* W4 = (const float4*)W;
  const float4* Xrow = (const float4*)&Xs[rg * 8][0];

  for (int k4 = 0; k4 < kD / 4; ++k4) {
    float4 w0 = W4[(size_t)(4 * k4 + 0) * 64 + j];
    float4 w1 = W4[(size_t)(4 * k4 + 1) * 64 + j];
    float4 w2 = W4[(size_t)(4 * k4 + 2) * 64 + j];
    float4 w3 = W4[(size_t)(4 * k4 + 3) * 64 + j];
#pragma unroll
    for (int i = 0; i < 8; ++i) {
      float4 x = Xrow[i * 64 + k4];
      acc[i].x = fmaf(x.x, w0.x, fmaf(x.y, w1.x, fmaf(x.z, w2.x, fmaf(x.w, w3.x, acc[i].x))));
      acc[i].y = fmaf(x.x, w0.y, fmaf(x.y, w1.y, fmaf(x.z, w2.y, fmaf(x.w, w3.y, acc[i].y))));
      acc[i].z = fmaf(x.x, w0.z, fmaf(x.y, w1.z, fmaf(x.z, w2.z, fmaf(x.w, w3.z, acc[i].z))));
      acc[i].w = fmaf(x.x, w0.w, fmaf(x.y, w1.w, fmaf(x.z, w2.w, fmaf(x.w, w3.w, acc[i].w))));
    }
  }
  float4* XW4 = (float4*)XW;
#pragma unroll
  for (int i = 0; i < 8; ++i)
    XW4[(size_t)(m0 + rg * 8 + i) * 64 + j] = acc[i];
}

// ---------------------------------------------------------------------------
// Kernel B: GK[b,t,s] = inputs[b,t,:] . keys[s,:], t < lengths[b] only. (unchanged)
// ---------------------------------------------------------------------------
__global__ __launch_bounds__(256, 4)
void gk_kernel(const float* __restrict__ inputs, const float* __restrict__ keys,
               const int* __restrict__ lengths, float* __restrict__ GK) {
  const int b = blockIdx.x;
  const int tid = threadIdx.x;
  const int lane = tid & 63;
  const int wid = tid >> 6;
  const int len = lengths[b];

  __shared__ float4 Ks4[kS * 64];
  for (int i = tid; i < kS * 64; i += 256) Ks4[i] = ((const float4*)keys)[i];
  __syncthreads();

  const float4* X4 = (const float4*)inputs;
  for (int t = wid; t < len; t += 4) {
    float4 x = X4[((size_t)b * kT + t) * 64 + lane];
    float p[kS];
#pragma unroll
    for (int s = 0; s < kS; ++s) {
      float4 kk = Ks4[s * 64 + lane];
      p[s] = fmaf(x.x, kk.x, fmaf(x.y, kk.y, fmaf(x.z, kk.z, x.w * kk.w)));
    }
#pragma unroll
    for (int off = 32; off >= 1; off >>= 1) {
#pragma unroll
      for (int s = 0; s < kS; ++s) p[s] += __shfl_xor(p[s], off, 64);
    }
    if (lane == 0) {
      float* g = GK + ((size_t)b * kT + t) * kS;
#pragma unroll
      for (int s = 0; s < kS; ++s) g[s] = p[s];
    }
  }
}

// ---------------------------------------------------------------------------
// Kernel S: rank lengths descending (stable). order[r] = batch with rank r.
// ---------------------------------------------------------------------------
__global__ __launch_bounds__(512)
void sort_lengths_kernel(const int* __restrict__ lengths, int* __restrict__ order) {
  __shared__ int L[kB];
  const int i = threadIdx.x;
  L[i] = lengths[i];
  __syncthreads();
  const int li = L[i];
  int r = 0;
  for (int j = 0; j < kB; ++j) {
    const int lj = L[j];
    r += (lj > li || (lj == li && j < i)) ? 1 : 0;
  }
  order[r] = i;
}

// ---------------------------------------------------------------------------
// Kernel C (rec6): 256 blocks x 1024 threads, paired batches (bA long, bB
// short; sorted). R2 post-mortem: at grid=256 the compiler provisioned for a
// phantom 2nd block/CU (VGPR_Count=64) and scratch-spilled 18 GB/dispatch.
// Fixes here:
//  * __launch_bounds__(1024, 4): declare 4 waves/SIMD == exactly 1 block/CU,
//    licensing the 128-reg budget.
//  * Peak live set cut ~130 -> ~114: matmul split into two s-passes
//    (C[4] float4 = 16 regs, not C[8] = 32); xwB/gkB loads deferred to after
//    the A-matmul (covered by B-matmul latency).
//  * Epilogue table reads halved: each lane reads its 8-slot half (2 x b128,
//    2-way banks instead of 4-way) and finishes with __shfl_xor(.,8)
//    (partner lane has the same s8).
// Thread (w=tid>>6, jj=lane>>4, q=lane&15): cols 4cg..4cg+3 (cg=w*4+jj),
// k-chunk [16q,16q+16), u4[16]=64 VGPR. k-reduction: DPP xor1,xor2,mirror7,
// mirror15 (pure VALU). Lane finalizes state row s8=q&7; only q<8 writes.
// ---------------------------------------------------------------------------
__global__ __launch_bounds__(1024, 4)
void dynmem_rec6_kernel(const float* __restrict__ inputs,   // [B,T,D]
                        const int*   __restrict__ lengths,  // [B]
                        const float* __restrict__ keys,     // [S,D]
                        const float* __restrict__ U,        // [D,D]
                        const float* __restrict__ V,        // [D,D]
                        const float* __restrict__ gate_bias,
                        const float* __restrict__ state_bias,
                        const float* __restrict__ XW,       // [B,T,D]
                        const float* __restrict__ GK,       // [B,T,S]
                        const int*   __restrict__ order,    // [B] desc by length
                        float* __restrict__ out)            // [B,S,D]
{
  const int blk = blockIdx.x;
  const int bA = order[blk];
  const int bB = order[kB - 1 - blk];
  const int tid = threadIdx.x;
  const int w = tid >> 6;          // 0..15
  const int lane = tid & 63;
  const int q = lane & 15;         // k-chunk index (16 k each)
  const int jj = lane >> 4;        // 0..3
  const int cg = w * 4 + jj;       // 0..63
  const int c0 = 4 * cg;
  const int c0p = physk(c0);       // 4 cols contiguous within a 32-group
  const int s8 = q & 7;            // state row this lane finalizes
  const int hoff = q & 8;          // which 8-slot half of the red tables

  __shared__ float StA[kS * kStRow];
  __shared__ float StB[kS * kStRow];
  __shared__ float KVL[kS * kD];
  __shared__ float redGA[kS * kRedRow], redGB[kS * kRedRow];
  __shared__ float redNA[kS * kRedRow], redNB[kS * kRedRow];

  // init both states = keys (padded layout)
  for (int i = tid; i < kS * kD; i += 1024) {
    int s = i >> 8, dd = i & 255;
    float kv = keys[i];
    int pa = s * kStRow + physk(dd);
    StA[pa] = kv;
    StB[pa] = kv;
  }

  // persistent U slice: rows 16q..16q+15, cols c0..c0+3 (64 VGPRs)
  float4 u4[16];
  const int kbase = 16 * q;
#pragma unroll
  for (int kk = 0; kk < 16; ++kk)
    u4[kk] = *(const float4*)(U + (size_t)(kbase + kk) * kD + c0);

  // KV[s][d] = (keys @ V)[s][d] + state_bias[d]; thread (h4,d) does rows h4, h4+4.
  {
    const int h4 = tid >> 8, d = tid & 255;   // h4 in 0..3
    float a0 = 0.f, a1 = 0.f;
    const float* Vc = V + d;
    const float* K0 = keys + (size_t)h4 * kD;
    const float* K1 = keys + (size_t)(h4 + 4) * kD;
    for (int k = 0; k < kD; ++k) {
      float v = Vc[(size_t)k * kD];
      a0 = fmaf(K0[k], v, a0);
      a1 = fmaf(K1[k], v, a1);
    }
    float sb = state_bias[d];
    KVL[h4 * kD + d] = a0 + sb;
    KVL[(h4 + 4) * kD + d] = a1 + sb;
  }

  const float gb = gate_bias[0];
  int lenA = lengths[bA]; lenA = lenA < 0 ? 0 : (lenA > kT ? kT : lenA);
  int lenB = lengths[bB]; lenB = lenB < 0 ? 0 : (lenB > kT ? kT : lenB);
  // sorted desc => lenA >= lenB; loop runs lenA steps.

  __syncthreads();  // states + KVL ready

  float4 srA = *(const float4*)(StA + s8 * kStRow + c0p);
  float4 srB = *(const float4*)(StB + s8 * kStRow + c0p);
  const float* SA = StA + physk(kbase);   // physical base of this k-chunk
  const float* SB = StB + physk(kbase);

  for (int t = 0; t < lenA; ++t) {
    const bool dB = t < lenB;
    const size_t baseA = ((size_t)bA * kT + t) * (size_t)kD;
    const size_t baseB = ((size_t)bB * kT + t) * (size_t)kD;

    // A-operand prefetch (latency hides under gate + matmuls)
    const float4 xwA = *(const float4*)(XW + baseA + c0);
    const float gkA = GK[((size_t)bA * kT + t) * kS + s8];

    // ---- gate partials for s=s8 over own 4 state cols ----
    {
      float4 xA = *(const float4*)(inputs + baseA + c0);
      float pg = fmaf(xA.x, srA.x, fmaf(xA.y, srA.y, fmaf(xA.z, srA.z, xA.w * srA.w)));
      pg += __shfl_xor(pg, 16, 64);
      pg += __shfl_xor(pg, 32, 64);
      if (lane < 8) redGA[lane * kRedRow + w] = pg;
    }
    if (dB) {
      float4 xB = *(const float4*)(inputs + baseB + c0);
      float pg = fmaf(xB.x, srB.x, fmaf(xB.y, srB.y, fmaf(xB.z, srB.z, xB.w * srB.w)));
      pg += __shfl_xor(pg, 16, 64);
      pg += __shfl_xor(pg, 32, 64);
      if (lane < 8) redGB[lane * kRedRow + w] = pg;
    }

    // ---- matmul A: two s-passes of 4 rows each (C[4] = 16 regs peak) ----
    float4 cA;
    {
      float4 C[4];
#pragma unroll
      for (int s = 0; s < 4; ++s) C[s] = make_float4(0.f, 0.f, 0.f, 0.f);
#pragma unroll
      for (int k4 = 0; k4 < 4; ++k4) {
        const float4 u0 = u4[4 * k4 + 0], u1 = u4[4 * k4 + 1];
        const float4 u2 = u4[4 * k4 + 2], u3 = u4[4 * k4 + 3];
#pragma unroll
        for (int s = 0; s < 4; ++s) {
          float4 sv = *(const float4*)(SA + s * kStRow + 4 * k4);
          C[s].x = fmaf(sv.x, u0.x, fmaf(sv.y, u1.x, fmaf(sv.z, u2.x, fmaf(sv.w, u3.x, C[s].x))));
          C[s].y = fmaf(sv.x, u0.y, fmaf(sv.y, u1.y, fmaf(sv.z, u2.y, fmaf(sv.w, u3.y, C[s].y))));
          C[s].z = fmaf(sv.x, u0.z, fmaf(sv.y, u1.z, fmaf(sv.z, u2.z, fmaf(sv.w, u3.z, C[s].z))));
          C[s].w = fmaf(sv.x, u0.w, fmaf(sv.y, u1.w, fmaf(sv.z, u2.w, fmaf(sv.w, u3.w, C[s].w))));
        }
      }
#pragma unroll
      for (int s = 0; s < 4; ++s) {
        C[s] = dpp_add4<0xB1>(C[s]);
        C[s] = dpp_add4<0x4E>(C[s]);
        C[s] = dpp_add4<0x141>(C[s]);
        C[s] = dpp_add4<0x140>(C[s]);
      }
      cA = C[0];
#pragma unroll
      for (int s = 1; s < 4; ++s) if (s8 == s) cA = C[s];
#pragma unroll
      for (int s = 0; s < 4; ++s) C[s] = make_float4(0.f, 0.f, 0.f, 0.f);
#pragma unroll
      for (int k4 = 0; k4 < 4; ++k4) {
        const float4 u0 = u4[4 * k4 + 0], u1 = u4[4 * k4 + 1];
        const float4 u2 = u4[4 * k4 + 2], u3 = u4[4 * k4 + 3];
#pragma unroll
        for (int s = 0; s < 4; ++s) {
          float4 sv = *(const float4*)(SA + (s + 4) * kStRow + 4 * k4);
          C[s].x = fmaf(sv.x, u0.x, fmaf(sv.y, u1.x, fmaf(sv.z, u2.x, fmaf(sv.w, u3.x, C[s].x))));
          C[s].y = fmaf(sv.x, u0.y, fmaf(sv.y, u1.y, fmaf(sv.z, u2.y, fmaf(sv.w, u3.y, C[s].y))));
          C[s].z = fmaf(sv.x, u0.z, fmaf(sv.y, u1.z, fmaf(sv.z, u2.z, fmaf(sv.w, u3.z, C[s].z))));
          C[s].w = fmaf(sv.x, u0.w, fmaf(sv.y, u1.w, fmaf(sv.z, u2.w, fmaf(sv.w, u3.w, C[s].w))));
        }
      }
#pragma unroll
      for (int s = 0; s < 4; ++s) {
        C[s] = dpp_add4<0xB1>(C[s]);
        C[s] = dpp_add4<0x4E>(C[s]);
        C[s] = dpp_add4<0x141>(C[s]);
        C[s] = dpp_add4<0x140>(C[s]);
      }
#pragma unroll
      for (int s = 0; s < 4; ++s) if (s8 == s + 4) cA = C[s];
    }

    // B-operand loads (latency hides under the B matmul)
    float4 xwB = make_float4(0.f, 0.f, 0.f, 0.f);
    float gkB = 0.f;
    if (dB) {
      xwB = *(const float4*)(XW + baseB + c0);
      gkB = GK[((size_t)bB * kT + t) * kS + s8];
    }

    // ---- matmul B: same two-pass structure ----
    float4 cB = make_float4(0.f, 0.f, 0.f, 0.f);
    if (dB) {
      float4 C[4];
#pragma unroll
      for (int s = 0; s < 4; ++s) C[s] = make_float4(0.f, 0.f, 0.f, 0.f);
#pragma unroll
      for (int k4 = 0; k4 < 4; ++k4) {
        const float4 u0 = u4[4 * k4 + 0], u1 = u4[4 * k4 + 1];
        const float4 u2 = u4[4 * k4 + 2], u3 = u4[4 * k4 + 3];
#pragma unroll
        for (int s = 0; s < 4; ++s) {
          float4 sv = *(const float4*)(SB + s * kStRow + 4 * k4);
          C[s].x = fmaf(sv.x, u0.x, fmaf(sv.y, u1.x, fmaf(sv.z, u2.x, fmaf(sv.w, u3.x, C[s].x))));
          C[s].y = fmaf(sv.x, u0.y, fmaf(sv.y, u1.y, fmaf(sv.z, u2.y, fmaf(sv.w, u3.y, C[s].y))));
          C[s].z = fmaf(sv.x, u0.z, fmaf(sv.y, u1.z, fmaf(sv.z, u2.z, fmaf(sv.w, u3.z, C[s].z))));
          C[s].w = fmaf(sv.x, u0.w, fmaf(sv.y, u1.w, fmaf(sv.z, u2.w, fmaf(sv.w, u3.w, C[s].w))));
        }
      }
#pragma unroll
      for (int s = 0; s < 4; ++s) {
        C[s] = dpp_add4<0xB1>(C[s]);
        C[s] = dpp_add4<0x4E>(C[s]);
        C[s] = dpp_add4<0x141>(C[s]);
        C[s] = dpp_add4<0x140>(C[s]);
      }
      cB = C[0];
#pragma unroll
      for (int s = 1; s < 4; ++s) if (s8 == s) cB = C[s];
#pragma unroll
      for (int s = 0; s < 4; ++s) C[s] = make_float4(0.f, 0.f, 0.f, 0.f);
#pragma unroll
      for (int k4 = 0; k4 < 4; ++k4) {
        const float4 u0 = u4[4 * k4 + 0], u1 = u4[4 * k4 + 1];
        const float4 u2 = u4[4 * k4 + 2], u3 = u4[4 * k4 + 3];
#pragma unroll
        for (int s = 0; s < 4; ++s) {
          float4 sv = *(const float4*)(SB + (s + 4) * kStRow + 4 * k4);
          C[s].x = fmaf(sv.x, u0.x, fmaf(sv.y, u1.x, fmaf(sv.z, u2.x, fmaf(sv.w, u3.x, C[s].x))));
          C[s].y = fmaf(sv.x, u0.y, fmaf(sv.y, u1.y, fmaf(sv.z, u2.y, fmaf(sv.w, u3.y, C[s].y))));
          C[s].z = fmaf(sv.x, u0.z, fmaf(sv.y, u1.z, fmaf(sv.z, u2.z, fmaf(sv.w, u3.z, C[s].z))));
          C[s].w = fmaf(sv.x, u0.w, fmaf(sv.y, u1.w, fmaf(sv.z, u2.w, fmaf(sv.w, u3.w, C[s].w))));
        }
      }
#pragma unroll
      for (int s = 0; s < 4; ++s) {
        C[s] = dpp_add4<0xB1>(C[s]);
        C[s] = dpp_add4<0x4E>(C[s]);
        C[s] = dpp_add4<0x141>(C[s]);
        C[s] = dpp_add4<0x140>(C[s]);
      }
#pragma unroll
      for (int s = 0; s < 4; ++s) if (s8 == s + 4) cB = C[s];
    }

    __syncthreads();  // B1: redG* complete; all St* matmul reads done

    const float4 kvq = *(const float4*)(KVL + s8 * kD + c0);
    float4 hA = make_float4(0.f, 0.f, 0.f, 0.f);
    float4 hB = make_float4(0.f, 0.f, 0.f, 0.f);
    {
      // halved table read (own 8-slot half) + cross-half shfl
      const float* rg = redGA + s8 * kRedRow + hoff;
      float4 ra = *(const float4*)(rg);
      float4 rb = *(const float4*)(rg + 4);
      float gh = ((ra.x + ra.y) + (ra.z + ra.w)) + ((rb.x + rb.y) + (rb.z + rb.w));
      float gs = gh + __shfl_xor(gh, 8, 64) + gkA + gb;
      float g = 1.f / (1.f + expf(-gs));
      float t0 = cA.x + kvq.x + xwA.x; t0 = t0 > 0.f ? t0 : expm1f(t0);
      float t1 = cA.y + kvq.y + xwA.y; t1 = t1 > 0.f ? t1 : expm1f(t1);
      float t2 = cA.z + kvq.z + xwA.z; t2 = t2 > 0.f ? t2 : expm1f(t2);
      float t3 = cA.w + kvq.w + xwA.w; t3 = t3 > 0.f ? t3 : expm1f(t3);
      hA.x = fmaf(g, t0, srA.x);
      hA.y = fmaf(g, t1, srA.y);
      hA.z = fmaf(g, t2, srA.z);
      hA.w = fmaf(g, t3, srA.w);
      float pn = fmaf(hA.x, hA.x, fmaf(hA.y, hA.y, fmaf(hA.z, hA.z, hA.w * hA.w)));
      pn += __shfl_xor(pn, 16, 64);
      pn += __shfl_xor(pn, 32, 64);
      if (lane < 8) redNA[lane * kRedRow + w] = pn;
    }
    if (dB) {
      const float* rg = redGB + s8 * kRedRow + hoff;
      float4 ra = *(const float4*)(rg);
      float4 rb = *(const float4*)(rg + 4);
      float gh = ((ra.x + ra.y) + (ra.z + ra.w)) + ((rb.x + rb.y) + (rb.z + rb.w));
      float gs = gh + __shfl_xor(gh, 8, 64) + gkB + gb;
      float g = 1.f / (1.f + expf(-gs));
      float t0 = cB.x + kvq.x + xwB.x; t0 = t0 > 0.f ? t0 : expm1f(t0);
      float t1 = cB.y + kvq.y + xwB.y; t1 = t1 > 0.f ? t1 : expm1f(t1);
      float t2 = cB.z + kvq.z + xwB.z; t2 = t2 > 0.f ? t2 : expm1f(t2);
      float t3 = cB.w + kvq.w + xwB.w; t3 = t3 > 0.f ? t3 : expm1f(t3);
      hB.x = fmaf(g, t0, srB.x);
      hB.y = fmaf(g, t1, srB.y);
      hB.z = fmaf(g, t2, srB.z);
      hB.w = fmaf(g, t3, srB.w);
      float pn = fmaf(hB.x, hB.x, fmaf(hB.y, hB.y, fmaf(hB.z, hB.z, hB.w * hB.w)));
      pn += __shfl_xor(pn, 16, 64);
      pn += __shfl_xor(pn, 32, 64);
      if (lane < 8) redNB[lane * kRedRow + w] = pn;
    }
    __syncthreads();  // B2: redN* complete

    {
      const float* rn = redNA + s8 * kRedRow + hoff;
      float4 na = *(const float4*)(rn);
      float4 nb = *(const float4*)(rn + 4);
      float nh = ((na.x + na.y) + (na.z + na.w)) + ((nb.x + nb.y) + (nb.z + nb.w));
      float ns = nh + __shfl_xor(nh, 8, 64);
      float inh = 1.f / fmaxf(sqrtf(ns), 1e-12f);
      srA.x = hA.x * inh; srA.y = hA.y * inh; srA.z = hA.z * inh; srA.w = hA.w * inh;
      if (q < 8) *(float4*)(StA + s8 * kStRow + c0p) = srA;
    }
    if (dB) {
      const float* rn = redNB + s8 * kRedRow + hoff;
      float4 na = *(const float4*)(rn);
      float4 nb = *(const float4*)(rn + 4);
      float nh = ((na.x + na.y) + (na.z + na.w)) + ((nb.x + nb.y) + (nb.z + nb.w));
      float ns = nh + __shfl_xor(nh, 8, 64);
      float inh = 1.f / fmaxf(sqrtf(ns), 1e-12f);
      srB.x = hB.x * inh; srB.y = hB.y * inh; srB.z = hB.z * inh; srB.w = hB.w * inh;
      if (q < 8) *(float4*)(StB + s8 * kStRow + c0p) = srB;
    }
    __syncthreads();  // B3: new states visible for next step
  }

  // final states -> out
  for (int i = tid; i < kS * kD; i += 1024) {
    int s = i >> 8, dd = i & 255;
    int pa = s * kStRow + physk(dd);
    out[(size_t)bA * kS * kD + i] = StA[pa];
    out[(size_t)bB * kS * kD + i] = StB[pa];
  }
}

extern "C" void kernel_launch(void* const* d_in, const int* in_sizes, int n_in,
                              void* d_out, int out_size, void* d_ws, size_t ws_size,
                              hipStream_t stream) {
  const float* inputs     = (const float*)d_in[0];
  const int*   lengths    = (const int*)  d_in[1];
  const float* keys       = (const float*)d_in[2];
  const float* U          = (const float*)d_in[3];
  const float* V          = (const float*)d_in[4];
  const float* W          = (const float*)d_in[5];
  const float* gate_bias  = (const float*)d_in[6];
  const float* state_bias = (const float*)d_in[7];

  const size_t xw_elems = (size_t)kB * kT * kD;
  const size_t gk_elems = (size_t)kB * kT * kS;
  float* XW = (float*)d_ws;
  float* GK = (float*)d_ws + xw_elems;
  int*   order = (int*)((float*)d_ws + xw_elems + gk_elems);

  sort_lengths_kernel<<<dim3(1), dim3(512), 0, stream>>>(lengths, order);
  xw_gemm_kernel<<<dim3((kB * kT) / 32), dim3(256), 0, stream>>>(inputs, W, lengths, XW);
  gk_kernel<<<dim3(kB), dim3(256), 0, stream>>>(inputs, keys, lengths, GK);
  dynmem_rec6_kernel<<<dim3(kB / 2), dim3(1024), 0, stream>>>(
      inputs, lengths, keys, U, V, gate_bias, state_bias, XW, GK, order, (float*)d_out);
}

// Round 4
// 2369.258 us; speedup vs baseline: 2.0897x; 2.0055x over previous
//
#include <hip/hip_runtime.h>
#include <math.h>

namespace {
constexpr int kB = 512;
constexpr int kT = 256;
constexpr int kD = 256;
constexpr int kS = 8;
constexpr int kStRow = 292;  // 288 data (physk layout) + 4; 292 % 32 == 4
constexpr int kRedRow = 20;  // reduction table row stride: 16 wave slots + pad

__device__ __forceinline__ int physk(int k) { return k + ((k >> 5) << 2); }

// DPP cross-lane adds (VALU pipe — zero DS traffic). HW-validated R2/R3.
//   0xB1  quad_perm [1,0,3,2]  == xor 1
//   0x4E  quad_perm [2,3,0,1]  == xor 2
//   0x141 row_half_mirror      == xor 7 within an 8-group (valid once quads
//         are uniform, i.e. after xor1+xor2 -> yields full 8-lane sum)
template <int CTRL>
__device__ __forceinline__ float dpp_add(float v) {
  int p = __builtin_amdgcn_update_dpp(0, __float_as_int(v), CTRL, 0xF, 0xF, false);
  return v + __int_as_float(p);
}
}

// ---------------------------------------------------------------------------
// Kernel A: XW[b,t,:] = inputs[b,t,:] @ W, skipping t >= lengths[b]. (unchanged)
// ---------------------------------------------------------------------------
__global__ __launch_bounds__(256, 2)
void xw_gemm_kernel(const float* __restrict__ X, const float* __restrict__ W,
                    const int* __restrict__ lengths, float* __restrict__ XW) {
  const int m0 = blockIdx.x * 32;
  const int b = m0 >> 8;
  const int t0 = m0 & 255;
  if (t0 >= lengths[b]) return;

  __shared__ float Xs[32][kD];
  const int tid = threadIdx.x;
  const int j  = tid & 63;
  const int rg = tid >> 6;

  const float4* Xg4 = (const float4*)(X + (size_t)m0 * kD);
  float4* Xs4 = (float4*)&Xs[0][0];
  for (int i = tid; i < 32 * kD / 4; i += 256) Xs4[i] = Xg4[i];
  __syncthreads();

  float4 acc[8];
#pragma unroll
  for (int i = 0; i < 8; ++i) acc[i] = make_float4(0.f, 0.f, 0.f, 0.f);

  const float4* W4 = (const float4*)W;
  const float4* Xrow = (const float4*)&Xs[rg * 8][0];

  for (int k4 = 0; k4 < kD / 4; ++k4) {
    float4 w0 = W4[(size_t)(4 * k4 + 0) * 64 + j];
    float4 w1 = W4[(size_t)(4 * k4 + 1) * 64 + j];
    float4 w2 = W4[(size_t)(4 * k4 + 2) * 64 + j];
    float4 w3 = W4[(size_t)(4 * k4 + 3) * 64 + j];
#pragma unroll
    for (int i = 0; i < 8; ++i) {
      float4 x = Xrow[i * 64 + k4];
      acc[i].x = fmaf(x.x, w0.x, fmaf(x.y, w1.x, fmaf(x.z, w2.x, fmaf(x.w, w3.x, acc[i].x))));
      acc[i].y = fmaf(x.x, w0.y, fmaf(x.y, w1.y, fmaf(x.z, w2.y, fmaf(x.w, w3.y, acc[i].y))));
      acc[i].z = fmaf(x.x, w0.z, fmaf(x.y, w1.z, fmaf(x.z, w2.z, fmaf(x.w, w3.z, acc[i].z))));
      acc[i].w = fmaf(x.x, w0.w, fmaf(x.y, w1.w, fmaf(x.z, w2.w, fmaf(x.w, w3.w, acc[i].w))));
    }
  }
  float4* XW4 = (float4*)XW;
#pragma unroll
  for (int i = 0; i < 8; ++i)
    XW4[(size_t)(m0 + rg * 8 + i) * 64 + j] = acc[i];
}

// ---------------------------------------------------------------------------
// Kernel B: GK[b,t,s] = inputs[b,t,:] . keys[s,:], t < lengths[b] only. (unchanged)
// ---------------------------------------------------------------------------
__global__ __launch_bounds__(256, 4)
void gk_kernel(const float* __restrict__ inputs, const float* __restrict__ keys,
               const int* __restrict__ lengths, float* __restrict__ GK) {
  const int b = blockIdx.x;
  const int tid = threadIdx.x;
  const int lane = tid & 63;
  const int wid = tid >> 6;
  const int len = lengths[b];

  __shared__ float4 Ks4[kS * 64];
  for (int i = tid; i < kS * 64; i += 256) Ks4[i] = ((const float4*)keys)[i];
  __syncthreads();

  const float4* X4 = (const float4*)inputs;
  for (int t = wid; t < len; t += 4) {
    float4 x = X4[((size_t)b * kT + t) * 64 + lane];
    float p[kS];
#pragma unroll
    for (int s = 0; s < kS; ++s) {
      float4 kk = Ks4[s * 64 + lane];
      p[s] = fmaf(x.x, kk.x, fmaf(x.y, kk.y, fmaf(x.z, kk.z, x.w * kk.w)));
    }
#pragma unroll
    for (int off = 32; off >= 1; off >>= 1) {
#pragma unroll
      for (int s = 0; s < kS; ++s) p[s] += __shfl_xor(p[s], off, 64);
    }
    if (lane == 0) {
      float* g = GK + ((size_t)b * kT + t) * kS;
#pragma unroll
      for (int s = 0; s < kS; ++s) g[s] = p[s];
    }
  }
}

// ---------------------------------------------------------------------------
// Kernel S: rank lengths descending (stable). order[r] = batch with rank r.
// ---------------------------------------------------------------------------
__global__ __launch_bounds__(512)
void sort_lengths_kernel(const int* __restrict__ lengths, int* __restrict__ order) {
  __shared__ int L[kB];
  const int i = threadIdx.x;
  L[i] = lengths[i];
  __syncthreads();
  const int li = L[i];
  int r = 0;
  for (int j = 0; j < kB; ++j) {
    const int lj = L[j];
    r += (lj > li || (lj == li && j < i)) ? 1 : 0;
  }
  order[r] = i;
}

// ---------------------------------------------------------------------------
// Kernel C (rec7): 256 blocks x 1024 threads, paired sorted batches.
// R2/R3 post-mortem: at 1024 thr the backend ALWAYS splits the budget
// 64 arch-VGPR + 64 AGPR (VGPR_Count=64 in all of R0/R2/R3); rec3's ~105-reg
// live set fit, rec5/6's dual-batch ~135 did not -> 11 GB/dispatch scratch.
// rec7 therefore keeps rec3's EXACT proven-fit matmul shape:
//   thread (w=tid>>6, jj=lane>>3, q=lane&7): col-pair p=w*8+jj (cols 2p,2p+1),
//   k-chunk [32q,32q+32), u2[32] = 64 regs, C0[8]+C1[8] = 16 regs,
//   conflict-free q*36 state addressing (R0: 131K conflicts vs R3's 1.7e8),
// and adds only the ~8-reg dual-batch extension (srB, SB, xwB, gkB) for the
// sorted-pair tail fix (R1's win), plus register-free DS-pipe savings:
//  * k-split reduction via DPP {xor1,xor2,mirror7} on the VALU pipe instead
//    of __shfl_xor(1,2,4) ds_swizzles (~750 wave-DS-insts/CU-step removed).
//  * halved gate/norm table readback: own 8-slot half (2xb128) + shfl_xor(8).
//  * scalar GK load (one dword) instead of 2x float4 + cndmask chain.
// Estimated live set ~113 < 128 -> no spill.
// ---------------------------------------------------------------------------
__global__ __launch_bounds__(1024, 4)
void dynmem_rec7_kernel(const float* __restrict__ inputs,   // [B,T,D]
                        const int*   __restrict__ lengths,  // [B]
                        const float* __restrict__ keys,     // [S,D]
                        const float* __restrict__ U,        // [D,D]
                        const float* __restrict__ V,        // [D,D]
                        const float* __restrict__ gate_bias,
                        const float* __restrict__ state_bias,
                        const float* __restrict__ XW,       // [B,T,D]
                        const float* __restrict__ GK,       // [B,T,S]
                        const int*   __restrict__ order,    // [B] desc by length
                        float* __restrict__ out)            // [B,S,D]
{
  const int blk = blockIdx.x;
  const int bA = order[blk];
  const int bB = order[kB - 1 - blk];
  const int tid = threadIdx.x;
  const int w = tid >> 6;        // 0..15
  const int lane = tid & 63;
  const int q = lane & 7;        // k-chunk AND the state row this lane owns
  const int jj = lane >> 3;      // 0..7
  const int p = w * 8 + jj;      // col-pair index, 0..127
  const int c0 = 2 * p;
  const int c0p = physk(c0);     // both cols in same 32-group (c0 even)
  const int hoff = lane & 8;     // which 8-slot half of the red tables (jj bit0)

  __shared__ float StA[kS * kStRow];
  __shared__ float StB[kS * kStRow];
  __shared__ float KVL[kS * kD];
  __shared__ float redGA[kS * kRedRow], redGB[kS * kRedRow];
  __shared__ float redNA[kS * kRedRow], redNB[kS * kRedRow];

  // init both states = keys (padded layout)
  for (int i = tid; i < kS * kD; i += 1024) {
    int s = i >> 8, dd = i & 255;
    float kv = keys[i];
    int pa = s * kStRow + physk(dd);
    StA[pa] = kv;
    StB[pa] = kv;
  }

  // persistent U slice: rows q*32..q*32+31, cols c0..c0+1  (64 regs)
  float2 u2[32];
#pragma unroll
  for (int kk = 0; kk < 32; ++kk)
    u2[kk] = *(const float2*)(U + (size_t)(q * 32 + kk) * kD + c0);

  // KV[s][d] = (keys @ V)[s][d] + state_bias[d]; thread (h4,d) does rows h4, h4+4.
  {
    const int h4 = tid >> 8, d = tid & 255;   // h4 in 0..3
    float a0 = 0.f, a1 = 0.f;
    const float* Vc = V + d;
    const float* K0 = keys + (size_t)h4 * kD;
    const float* K1 = keys + (size_t)(h4 + 4) * kD;
    for (int k = 0; k < kD; ++k) {
      float v = Vc[(size_t)k * kD];
      a0 = fmaf(K0[k], v, a0);
      a1 = fmaf(K1[k], v, a1);
    }
    float sb = state_bias[d];
    KVL[h4 * kD + d] = a0 + sb;
    KVL[(h4 + 4) * kD + d] = a1 + sb;
  }

  const float gb = gate_bias[0];
  int lenA = lengths[bA]; lenA = lenA < 0 ? 0 : (lenA > kT ? kT : lenA);
  int lenB = lengths[bB]; lenB = lenB < 0 ? 0 : (lenB > kT ? kT : lenB);
  // sorted desc => lenA >= lenB

  __syncthreads();  // states + KVL ready

  const float2 kvq = *(const float2*)(KVL + q * kD + c0);
  float2 srA = *(const float2*)(StA + q * kStRow + c0p);
  float2 srB = *(const float2*)(StB + q * kStRow + c0p);

  const float* SA = StA + q * 36;  // physical base of 32-k chunk q within a row
  const float* SB = StB + q * 36;

  for (int t = 0; t < lenA; ++t) {
    const bool dB = t < lenB;
    const size_t baseA = ((size_t)bA * kT + t) * (size_t)kD;
    const size_t baseB = ((size_t)bB * kT + t) * (size_t)kD;

    // A-operand prefetch (latency hides under gate + matmul A)
    const float2 xwA = *(const float2*)(XW + baseA + c0);
    const float gkA = GK[((size_t)bA * kT + t) * kS + q];

    // ---- gate partials for s=q over own 2 state cols ----
    {
      float2 xA = *(const float2*)(inputs + baseA + c0);
      float pg = fmaf(xA.x, srA.x, xA.y * srA.y);
      pg += __shfl_xor(pg, 8, 64);
      pg += __shfl_xor(pg, 16, 64);
      pg += __shfl_xor(pg, 32, 64);
      if (lane < 8) redGA[lane * kRedRow + w] = pg;  // lane == q here
    }
    if (dB) {
      float2 xB = *(const float2*)(inputs + baseB + c0);
      float pg = fmaf(xB.x, srB.x, xB.y * srB.y);
      pg += __shfl_xor(pg, 8, 64);
      pg += __shfl_xor(pg, 16, 64);
      pg += __shfl_xor(pg, 32, 64);
      if (lane < 8) redGB[lane * kRedRow + w] = pg;
    }

    // ---- matmul A: C[s] over 32-k chunk q, 2 cols (U in registers) ----
    float caA, cbA, caB = 0.f, cbB = 0.f;
    {
      float C0[8], C1[8];
#pragma unroll
      for (int s = 0; s < 8; ++s) { C0[s] = 0.f; C1[s] = 0.f; }
#pragma unroll
      for (int k4 = 0; k4 < 8; ++k4) {
#pragma unroll
        for (int s = 0; s < 8; ++s) {
          float4 sv = *(const float4*)(SA + s * kStRow + 4 * k4);
          C0[s] = fmaf(sv.x, u2[4 * k4 + 0].x, C0[s]);
          C0[s] = fmaf(sv.y, u2[4 * k4 + 1].x, C0[s]);
          C0[s] = fmaf(sv.z, u2[4 * k4 + 2].x, C0[s]);
          C0[s] = fmaf(sv.w, u2[4 * k4 + 3].x, C0[s]);
          C1[s] = fmaf(sv.x, u2[4 * k4 + 0].y, C1[s]);
          C1[s] = fmaf(sv.y, u2[4 * k4 + 1].y, C1[s]);
          C1[s] = fmaf(sv.z, u2[4 * k4 + 2].y, C1[s]);
          C1[s] = fmaf(sv.w, u2[4 * k4 + 3].y, C1[s]);
        }
      }
      // k-split reduction across q (lane bits 0..2): pure-VALU DPP tree
#pragma unroll
      for (int s = 0; s < 8; ++s) {
        C0[s] = dpp_add<0xB1>(C0[s]);  C1[s] = dpp_add<0xB1>(C1[s]);
        C0[s] = dpp_add<0x4E>(C0[s]);  C1[s] = dpp_add<0x4E>(C1[s]);
        C0[s] = dpp_add<0x141>(C0[s]); C1[s] = dpp_add<0x141>(C1[s]);
      }
      caA = C0[0]; cbA = C1[0];
#pragma unroll
      for (int s = 1; s < 8; ++s) {
        if (q == s) { caA = C0[s]; cbA = C1[s]; }
      }
    }

    // B-operand loads (latency hides under matmul B)
    float2 xwB = make_float2(0.f, 0.f);
    float gkB = 0.f;
    if (dB) {
      xwB = *(const float2*)(XW + baseB + c0);
      gkB = GK[((size_t)bB * kT + t) * kS + q];
    }

    // ---- matmul B (accumulators reused — no extra liveness) ----
    if (dB) {
      float C0[8], C1[8];
#pragma unroll
      for (int s = 0; s < 8; ++s) { C0[s] = 0.f; C1[s] = 0.f; }
#pragma unroll
      for (int k4 = 0; k4 < 8; ++k4) {
#pragma unroll
        for (int s = 0; s < 8; ++s) {
          float4 sv = *(const float4*)(SB + s * kStRow + 4 * k4);
          C0[s] = fmaf(sv.x, u2[4 * k4 + 0].x, C0[s]);
          C0[s] = fmaf(sv.y, u2[4 * k4 + 1].x, C0[s]);
          C0[s] = fmaf(sv.z, u2[4 * k4 + 2].x, C0[s]);
          C0[s] = fmaf(sv.w, u2[4 * k4 + 3].x, C0[s]);
          C1[s] = fmaf(sv.x, u2[4 * k4 + 0].y, C1[s]);
          C1[s] = fmaf(sv.y, u2[4 * k4 + 1].y, C1[s]);
          C1[s] = fmaf(sv.z, u2[4 * k4 + 2].y, C1[s]);
          C1[s] = fmaf(sv.w, u2[4 * k4 + 3].y, C1[s]);
        }
      }
#pragma unroll
      for (int s = 0; s < 8; ++s) {
        C0[s] = dpp_add<0xB1>(C0[s]);  C1[s] = dpp_add<0xB1>(C1[s]);
        C0[s] = dpp_add<0x4E>(C0[s]);  C1[s] = dpp_add<0x4E>(C1[s]);
        C0[s] = dpp_add<0x141>(C0[s]); C1[s] = dpp_add<0x141>(C1[s]);
      }
      caB = C0[0]; cbB = C1[0];
#pragma unroll
      for (int s = 1; s < 8; ++s) {
        if (q == s) { caB = C0[s]; cbB = C1[s]; }
      }
    }

    __syncthreads();  // B1: redG* complete; all St* matmul reads done

    float2 hA = make_float2(0.f, 0.f), hB = make_float2(0.f, 0.f);
    {
      // halved table read (own 8-slot half) + cross-half shfl (lane^8 same q)
      const float* rg = redGA + q * kRedRow + hoff;
      float4 ra = *(const float4*)(rg);
      float4 rb = *(const float4*)(rg + 4);
      float gh = ((ra.x + ra.y) + (ra.z + ra.w)) + ((rb.x + rb.y) + (rb.z + rb.w));
      float gs = gh + __shfl_xor(gh, 8, 64) + gkA + gb;
      float g = 1.f / (1.f + expf(-gs));
      float t0 = caA + kvq.x + xwA.x; t0 = t0 > 0.f ? t0 : expm1f(t0);
      float t1 = cbA + kvq.y + xwA.y; t1 = t1 > 0.f ? t1 : expm1f(t1);
      hA.x = fmaf(g, t0, srA.x);
      hA.y = fmaf(g, t1, srA.y);
      float pn = fmaf(hA.x, hA.x, hA.y * hA.y);
      pn += __shfl_xor(pn, 8, 64);
      pn += __shfl_xor(pn, 16, 64);
      pn += __shfl_xor(pn, 32, 64);
      if (lane < 8) redNA[lane * kRedRow + w] = pn;
    }
    if (dB) {
      const float* rg = redGB + q * kRedRow + hoff;
      float4 ra = *(const float4*)(rg);
      float4 rb = *(const float4*)(rg + 4);
      float gh = ((ra.x + ra.y) + (ra.z + ra.w)) + ((rb.x + rb.y) + (rb.z + rb.w));
      float gs = gh + __shfl_xor(gh, 8, 64) + gkB + gb;
      float g = 1.f / (1.f + expf(-gs));
      float t0 = caB + kvq.x + xwB.x; t0 = t0 > 0.f ? t0 : expm1f(t0);
      float t1 = cbB + kvq.y + xwB.y; t1 = t1 > 0.f ? t1 : expm1f(t1);
      hB.x = fmaf(g, t0, srB.x);
      hB.y = fmaf(g, t1, srB.y);
      float pn = fmaf(hB.x, hB.x, hB.y * hB.y);
      pn += __shfl_xor(pn, 8, 64);
      pn += __shfl_xor(pn, 16, 64);
      pn += __shfl_xor(pn, 32, 64);
      if (lane < 8) redNB[lane * kRedRow + w] = pn;
    }
    __syncthreads();  // B2: redN* complete

    {
      const float* rn = redNA + q * kRedRow + hoff;
      float4 na = *(const float4*)(rn);
      float4 nb = *(const float4*)(rn + 4);
      float nh = ((na.x + na.y) + (na.z + na.w)) + ((nb.x + nb.y) + (nb.z + nb.w));
      float ns = nh + __shfl_xor(nh, 8, 64);
      float inh = 1.f / fmaxf(sqrtf(ns), 1e-12f);
      srA.x = hA.x * inh;
      srA.y = hA.y * inh;
      *(float2*)(StA + q * kStRow + c0p) = srA;
    }
    if (dB) {
      const float* rn = redNB + q * kRedRow + hoff;
      float4 na = *(const float4*)(rn);
      float4 nb = *(const float4*)(rn + 4);
      float nh = ((na.x + na.y) + (na.z + na.w)) + ((nb.x + nb.y) + (nb.z + nb.w));
      float ns = nh + __shfl_xor(nh, 8, 64);
      float inh = 1.f / fmaxf(sqrtf(ns), 1e-12f);
      srB.x = hB.x * inh;
      srB.y = hB.y * inh;
      *(float2*)(StB + q * kStRow + c0p) = srB;
    }
    __syncthreads();  // B3: new states visible for next step
  }

  // final states -> out
  for (int i = tid; i < kS * kD; i += 1024) {
    int s = i >> 8, dd = i & 255;
    int pa = s * kStRow + physk(dd);
    out[(size_t)bA * kS * kD + i] = StA[pa];
    out[(size_t)bB * kS * kD + i] = StB[pa];
  }
}

extern "C" void kernel_launch(void* const* d_in, const int* in_sizes, int n_in,
                              void* d_out, int out_size, void* d_ws, size_t ws_size,
                              hipStream_t stream) {
  const float* inputs     = (const float*)d_in[0];
  const int*   lengths    = (const int*)  d_in[1];
  const float* keys       = (const float*)d_in[2];
  const float* U          = (const float*)d_in[3];
  const float* V          = (const float*)d_in[4];
  const float* W          = (const float*)d_in[5];
  const float* gate_bias  = (const float*)d_in[6];
  const float* state_bias = (const float*)d_in[7];

  const size_t xw_elems = (size_t)kB * kT * kD;
  const size_t gk_elems = (size_t)kB * kT * kS;
  float* XW = (float*)d_ws;
  float* GK = (float*)d_ws + xw_elems;
  int*   order = (int*)((float*)d_ws + xw_elems + gk_elems);

  sort_lengths_kernel<<<dim3(1), dim3(512), 0, stream>>>(lengths, order);
  xw_gemm_kernel<<<dim3((kB * kT) / 32), dim3(256), 0, stream>>>(inputs, W, lengths, XW);
  gk_kernel<<<dim3(kB), dim3(256), 0, stream>>>(inputs, keys, lengths, GK);
  dynmem_rec7_kernel<<<dim3(kB / 2), dim3(1024), 0, stream>>>(
      inputs, lengths, keys, U, V, gate_bias, state_bias, XW, GK, order, (float*)d_out);
}